// Round 5
// baseline (164.360 us; speedup 1.0000x reference)
//
#include <hip/hip_runtime.h>

// ConvCaps (Matrix Capsules w/ EM routing), MI355X fp32.
// One block per output position: 784 blocks x 512 threads (8 waves).
// Thread map: c  = wv*4 + (lane&3)   (class, 0..31)
//             ph = (lane>>2)&1       (pose-column half: jj in {0,1} or {2,3})
//             sub= lane>>3           (n-slice, 0..7), each owns 18 n's.
// Each thread accumulates 8 of the 16 vote elements -> persistent state
// halves (S1[8]+S2[8]) vs the 16-wide map, keeping VGPR<=64 which is the
// 2-blocks/CU residency boundary (r4 post-mortem: waves/SIMD=floor(256/VGPR)).
// r lives in LDS; E-step writes ph-partial ln_ap into two LDS halves and the
// softmax sums them (no per-n cross-lane shuffle).

namespace {

constexpr int OHW  = 14;
constexpr int NPOS = 4 * OHW * OHW;     // 784
constexpr int NN   = 144;               // 3*3*16
constexpr int CC   = 32;
constexpr int KPER = 18;                // n's per thread
constexpr float LAMB  = 0.01f;
constexpr float EPSF  = 1e-6f;
constexpr float LN2PI = 1.8378770664093453f;
constexpr int PSTR = 20;                // sP row stride (dwords)
constexpr int RS   = 33;                // ln_ap / r row stride (conflict-free)
constexpr int LHALF = NN * RS;          // 4752

__device__ __forceinline__ float rcpf(float x) { return __builtin_amdgcn_rcpf(x); }

// lane ^ 8 exchange via DPP row_ror:8 (rows of 16: (i+8)%16 == i^8)
__device__ __forceinline__ float xor8_dpp(float x) {
  int y = __builtin_amdgcn_update_dpp(0, __float_as_int(x), 0x128, 0xF, 0xF, true);
  return __int_as_float(y);
}

__global__ __launch_bounds__(512, 4)
void convcaps_em(const float* __restrict__ x,
                 const float* __restrict__ a,
                 const float* __restrict__ w,        // (144, 32, 4, 4)
                 const float* __restrict__ beta_u,
                 const float* __restrict__ beta_a,
                 const int*   __restrict__ iters_p,
                 float* __restrict__ out_mu,         // (4,14,14,32,16)
                 float* __restrict__ out_a)          // (4,14,14,32,1)
{
  __shared__ __align__(16) float sP[NN * PSTR];
  __shared__ float sA[NN];
  __shared__ float sL[2 * LHALF];   // [0]: r / ph0 ln_ap partial; [1]: ph1 partial

  const int tid = threadIdx.x;
  const int pos = blockIdx.x;
  const int b   = pos / (OHW * OHW);
  const int rem = pos - b * (OHW * OHW);
  const int oi  = rem / OHW;
  const int oj  = rem - oi * OHW;

  int iters = iters_p[0];
  iters = (iters < 1) ? 1 : (iters > 16 ? 16 : iters);

  // ---- stage pose patch (576 float4) + activations ----
  {
    {
      const int n = tid >> 2, j = tid & 3;
      const int kh = n / 48, kw = (n >> 4) % 3, bc = n & 15;
      const float4 val = *(const float4*)(x + ((((b * 16 + oi + kh) * 16) + (oj + kw)) * 256 + bc * 16 + j * 4));
      *(float4*)(sP + n * PSTR + j * 4) = val;
    }
    if (tid < 64) {
      const int g = 512 + tid;
      const int n = g >> 2, j = g & 3;
      const int kh = n / 48, kw = (n >> 4) % 3, bc = n & 15;
      const float4 val = *(const float4*)(x + ((((b * 16 + oi + kh) * 16) + (oj + kw)) * 256 + bc * 16 + j * 4));
      *(float4*)(sP + n * PSTR + j * 4) = val;
    }
    if (tid < NN) {
      const int kh = tid / 48, kw = (tid >> 4) % 3, bc = tid & 15;
      sA[tid] = a[(((b * 16 + oi + kh) * 16) + (oj + kw)) * 16 + bc];
    }
  }
  __syncthreads();

  const int lane = tid & 63;
  const int wv   = tid >> 6;                 // 0..7
  const int c    = wv * 4 + (lane & 3);      // 0..31
  const int ph   = (lane >> 2) & 1;          // 0..1
  const int sub  = lane >> 3;                // 0..7
  const int n0   = sub * KPER;
  const float bu = beta_u[c];
  const float ba = beta_a[c];
  // this thread's W slice: columns {2*ph, 2*ph+1} of each 4x4 W[n][c]
  const float* __restrict__ wcp = w + c * 16 + ph * 2;   // + n*512 + j*4

  // ---- init r[n][c] = a_in[n]/C. Writer (ph0) and readers (ph0,ph1) are
  // lanes of the same wave -> lockstep ordering, no barrier needed.
  if (ph == 0) {
    #pragma unroll
    for (int k = 0; k < KPER; ++k) sL[(n0 + k) * RS + c] = sA[n0 + k] * (1.0f / CC);
  }

  float S1[8], S2[8];   // after stats: S1 = mu (then B), S2 = hi (A)
  float logsum = 0.f, aout = 0.f, rs = 0.f;

  for (int it = 0; it < iters; ++it) {
    // ---- r_sum over n for class c ----
    float r0 = 0.f, r1 = 0.f;
    #pragma unroll
    for (int k = 0; k < KPER; k += 2) {
      r0 += sL[(n0 + k) * RS + c];
      r1 += sL[(n0 + k + 1) * RS + c];
    }
    rs = r0 + r1;
    rs += xor8_dpp(rs);
    rs += __shfl_xor(rs, 16);
    rs += __shfl_xor(rs, 32);
    const float inv = rcpf(rs + EPSF);

    // ---- M-step: S1/S2 over this thread's 18 n's x 8 vote elems ----
    #pragma unroll
    for (int p = 0; p < 8; ++p) { S1[p] = 0.f; S2[p] = 0.f; }

    #pragma unroll 2
    for (int k = 0; k < KPER; ++k) {
      const int n = n0 + k;
      const float coeff = sL[n * RS + c] * inv;
      const float* wb = wcp + n * 512;
      const float2 w0 = *(const float2*)(wb);
      const float2 w1 = *(const float2*)(wb + 4);
      const float2 w2 = *(const float2*)(wb + 8);
      const float2 w3 = *(const float2*)(wb + 12);
      #pragma unroll
      for (int i = 0; i < 4; ++i) {
        const float4 pr = *(const float4*)(sP + n * PSTR + i * 4);
        const float va = fmaf(pr.x, w0.x, fmaf(pr.y, w1.x, fmaf(pr.z, w2.x, pr.w * w3.x)));
        const float vb = fmaf(pr.x, w0.y, fmaf(pr.y, w1.y, fmaf(pr.z, w2.y, pr.w * w3.y)));
        const float ca = coeff * va, cb = coeff * vb;
        S1[2*i+0] += ca;  S2[2*i+0] = fmaf(ca, va, S2[2*i+0]);
        S1[2*i+1] += cb;  S2[2*i+1] = fmaf(cb, vb, S2[2*i+1]);
      }
    }

    // ---- reduce across the 8 sub-lanes (all lanes keep full sums) ----
    #pragma unroll
    for (int p = 0; p < 8; ++p) { S1[p] += xor8_dpp(S1[p]);       S2[p] += xor8_dpp(S2[p]);       }
    #pragma unroll
    for (int p = 0; p < 8; ++p) { S1[p] += __shfl_xor(S1[p], 16); S2[p] += __shfl_xor(S2[p], 16); }
    #pragma unroll
    for (int p = 0; p < 8; ++p) { S1[p] += __shfl_xor(S1[p], 32); S2[p] += __shfl_xor(S2[p], 32); }

    // ---- per-class stats: S1 -> mu, S2 -> hi = 0.5/sigma^2 ----
    const float g2 = 2.0f - rs * inv;        // 2 - sum(coeff), exact
    float ls0 = 0.f, ls1 = 0.f;
    #pragma unroll
    for (int p = 0; p < 8; p += 2) {
      const float m0 = S1[p], m1 = S1[p+1];
      float sg0 = S2[p]   - m0 * m0 * g2 + EPSF;
      float sg1 = S2[p+1] - m1 * m1 * g2 + EPSF;
      sg0 = fmaxf(sg0, 1e-12f);  sg1 = fmaxf(sg1, 1e-12f);
      ls0 += __logf(sg0);        ls1 += __logf(sg1);
      S2[p]   = 0.5f * rcpf(sg0);
      S2[p+1] = 0.5f * rcpf(sg1);
    }
    float lsh = ls0 + ls1;
    logsum = lsh + __shfl_xor(lsh, 4);       // combine ph halves
    const float cost = rs * (16.0f * bu + 0.5f * logsum);
    aout = rcpf(1.0f + __expf(-LAMB * (ba - cost)));

    if (it == iters - 1) {
      if (sub == 0) {
        float o[8];
        #pragma unroll
        for (int p = 0; p < 8; ++p) o[p] = __shfl_xor(S1[p], 4);   // partner's half
        if (ph == 0) {
          float4* om = (float4*)(out_mu + (size_t)pos * 512 + c * 16);
          #pragma unroll
          for (int i = 0; i < 4; ++i)
            om[i] = make_float4(S1[2*i], S1[2*i+1], o[2*i], o[2*i+1]);
          out_a[pos * CC + c] = aout;
        }
      }
    } else {
      // ---- E-step: ph-partial ln_ap. S2=A=hi, S1:=B=-2*hi*mu;
      // partial = [ph0: logterm] - sum_my8 (A v^2 + B v) - D_half
      float D = 0.f;
      #pragma unroll
      for (int p = 0; p < 8; ++p) {
        const float m = S1[p];
        D = fmaf(S2[p] * m, m, D);
        S1[p] = -2.0f * S2[p] * m;
      }
      const float logterm = __logf(aout + EPSF) - 0.5f * logsum - 8.0f * LN2PI;
      const float kc = (ph == 0 ? logterm : 0.0f) - D;
      float* __restrict__ sLp = sL + ph * LHALF;

      #pragma unroll 2
      for (int k = 0; k < KPER; ++k) {
        const int n = n0 + k;
        const float* wb = wcp + n * 512;
        const float2 w0 = *(const float2*)(wb);
        const float2 w1 = *(const float2*)(wb + 4);
        const float2 w2 = *(const float2*)(wb + 8);
        const float2 w3 = *(const float2*)(wb + 12);
        float s = 0.f;
        #pragma unroll
        for (int i = 0; i < 4; ++i) {
          const float4 pr = *(const float4*)(sP + n * PSTR + i * 4);
          const float va = fmaf(pr.x, w0.x, fmaf(pr.y, w1.x, fmaf(pr.z, w2.x, pr.w * w3.x)));
          const float vb = fmaf(pr.x, w0.y, fmaf(pr.y, w1.y, fmaf(pr.z, w2.y, pr.w * w3.y)));
          s = fmaf(fmaf(S2[2*i+0], va, S1[2*i+0]), va, s);
          s = fmaf(fmaf(S2[2*i+1], vb, S1[2*i+1]), vb, s);
        }
        sLp[n * RS + c] = kc - s;
      }
      __syncthreads();
      // ---- softmax over classes per n (2 threads/capsule), sum ph halves ----
      if (tid < 2 * NN) {
        const int n = tid >> 1, hf = (tid & 1) << 4;
        float xv[16];
        float mx = -3.0e38f;
        #pragma unroll
        for (int q = 0; q < 16; ++q) {
          xv[q] = sL[n * RS + hf + q] + sL[LHALF + n * RS + hf + q];
          mx = fmaxf(mx, xv[q]);
        }
        mx = fmaxf(mx, __shfl_xor(mx, 1));
        float ssum = 0.f;
        #pragma unroll
        for (int q = 0; q < 16; ++q) { xv[q] = __expf(xv[q] - mx); ssum += xv[q]; }
        ssum += __shfl_xor(ssum, 1);
        const float sc = sA[n] * rcpf(ssum);
        #pragma unroll
        for (int q = 0; q < 16; ++q) sL[n * RS + hf + q] = xv[q] * sc;
      }
      __syncthreads();
    }
  }
}

} // namespace

extern "C" void kernel_launch(void* const* d_in, const int* in_sizes, int n_in,
                              void* d_out, int out_size, void* d_ws, size_t ws_size,
                              hipStream_t stream) {
  const float* x  = (const float*)d_in[0];
  const float* a  = (const float*)d_in[1];
  const float* w  = (const float*)d_in[2];
  const float* bu = (const float*)d_in[3];
  const float* ba = (const float*)d_in[4];
  const int* iters = (const int*)d_in[5];

  float* out_mu = (float*)d_out;                       // 401408
  float* out_a  = out_mu + (size_t)NPOS * CC * 16;     // 25088

  convcaps_em<<<NPOS, 512, 0, stream>>>(x, a, w, bu, ba, iters, out_mu, out_a);
}

// Round 6
// 127.690 us; speedup vs baseline: 1.2872x; 1.2872x over previous
//
#include <hip/hip_runtime.h>

// ConvCaps (Matrix Capsules w/ EM routing), MI355X fp32.
// One block per output position: 784 blocks x 512 threads (8 waves).
// Thread map (r3 layout — empirically best): c = wv*4 + (lane&3) (0..31),
// sub = lane>>2 (0..15), each thread owns 9 consecutive n's and all 16 vote
// elements. r lives in LDS (thread writes/reads only its own entries).
// Diet vs r3: mu/hi aliased onto S1/S2 (keeps VGPR<=64, the 4-waves/SIMD
// boundary), v_rcp for all divides, S0 eliminated analytically, mask-8
// butterfly stage via DPP row_ror:8, Horner E-step, 2-thread softmax.

namespace {

constexpr int OHW  = 14;
constexpr int NPOS = 4 * OHW * OHW;     // 784
constexpr int NN   = 144;               // 3*3*16
constexpr int CC   = 32;
constexpr int KPER = 9;                 // n's per thread
constexpr float LAMB  = 0.01f;
constexpr float EPSF  = 1e-6f;
constexpr float LN2PI = 1.8378770664093453f;
constexpr int PSTR = 20;                // sP row stride (dwords)
constexpr int RS   = 33;                // r / ln_ap row stride

__device__ __forceinline__ float rcpf(float x) { return __builtin_amdgcn_rcpf(x); }

// lane ^ 8 exchange via DPP row_ror:8 (rows of 16: (i+8)%16 == i^8)
__device__ __forceinline__ float xor8_dpp(float x) {
  int y = __builtin_amdgcn_update_dpp(0, __float_as_int(x), 0x128, 0xF, 0xF, true);
  return __int_as_float(y);
}

__global__ __launch_bounds__(512, 2)
void convcaps_em(const float* __restrict__ x,
                 const float* __restrict__ a,
                 const float* __restrict__ w,        // (144, 32, 4, 4)
                 const float* __restrict__ beta_u,
                 const float* __restrict__ beta_a,
                 const int*   __restrict__ iters_p,
                 float* __restrict__ out_mu,         // (4,14,14,32,16)
                 float* __restrict__ out_a)          // (4,14,14,32,1)
{
  __shared__ __align__(16) float sP[NN * PSTR];
  __shared__ float sA[NN];
  __shared__ float sL[NN * RS];                      // r / ln_ap exchange

  const int tid = threadIdx.x;
  const int pos = blockIdx.x;
  const int b   = pos / (OHW * OHW);
  const int rem = pos - b * (OHW * OHW);
  const int oi  = rem / OHW;
  const int oj  = rem - oi * OHW;

  int iters = iters_p[0];
  iters = (iters < 1) ? 1 : (iters > 16 ? 16 : iters);

  // ---- stage pose patch (576 float4) + activations ----
  {
    {
      const int n = tid >> 2, j = tid & 3;
      const int kh = n / 48, kw = (n >> 4) % 3, bc = n & 15;
      const float4 val = *(const float4*)(x + ((((b * 16 + oi + kh) * 16) + (oj + kw)) * 256 + bc * 16 + j * 4));
      *(float4*)(sP + n * PSTR + j * 4) = val;
    }
    if (tid < 64) {
      const int g = 512 + tid;
      const int n = g >> 2, j = g & 3;
      const int kh = n / 48, kw = (n >> 4) % 3, bc = n & 15;
      const float4 val = *(const float4*)(x + ((((b * 16 + oi + kh) * 16) + (oj + kw)) * 256 + bc * 16 + j * 4));
      *(float4*)(sP + n * PSTR + j * 4) = val;
    }
    if (tid < NN) {
      const int kh = tid / 48, kw = (tid >> 4) % 3, bc = tid & 15;
      sA[tid] = a[(((b * 16 + oi + kh) * 16) + (oj + kw)) * 16 + bc];
    }
  }
  __syncthreads();

  const int lane = tid & 63;
  const int wv   = tid >> 6;                 // 0..7
  const int c    = wv * 4 + (lane & 3);      // 0..31
  const int sub  = lane >> 2;                // 0..15
  const int n0   = sub * KPER;
  const float bu = beta_u[c];
  const float ba = beta_a[c];
  const float* __restrict__ wc = w + c * 16; // + n*512

  // init r[n][c] = a_in[n]/C  (each thread writes exactly its own entries)
  #pragma unroll
  for (int k = 0; k < KPER; ++k) sL[(n0 + k) * RS + c] = sA[n0 + k] * (1.0f / CC);

  // S1: partial sums -> mu -> B coefficients.  S2: partial sq-sums -> hi -> A.
  float S1[16], S2[16];

  for (int it = 0; it < iters; ++it) {
    // ---- r_sum over n for class c ----
    float rs = 0.f;
    #pragma unroll
    for (int k = 0; k < KPER; ++k) rs += sL[(n0 + k) * RS + c];
    rs += __shfl_xor(rs, 4);
    rs += xor8_dpp(rs);
    rs += __shfl_xor(rs, 16);
    rs += __shfl_xor(rs, 32);
    const float inv = rcpf(rs + EPSF);

    // ---- M-step: S1/S2 over this thread's 9 n's (votes recomputed) ----
    #pragma unroll
    for (int p = 0; p < 16; ++p) { S1[p] = 0.f; S2[p] = 0.f; }

    #pragma unroll 3
    for (int k = 0; k < KPER; ++k) {
      const int n = n0 + k;
      const float4* Wp = (const float4*)(wc + n * 512);
      const float4 w0 = Wp[0], w1 = Wp[1], w2 = Wp[2], w3 = Wp[3];
      const float coeff = sL[n * RS + c] * inv;
      #pragma unroll
      for (int i = 0; i < 4; ++i) {
        const float4 pr = *(const float4*)(sP + n * PSTR + i * 4);
        const float v0 = fmaf(pr.x, w0.x, fmaf(pr.y, w1.x, fmaf(pr.z, w2.x, pr.w * w3.x)));
        const float v1 = fmaf(pr.x, w0.y, fmaf(pr.y, w1.y, fmaf(pr.z, w2.y, pr.w * w3.y)));
        const float v2 = fmaf(pr.x, w0.z, fmaf(pr.y, w1.z, fmaf(pr.z, w2.z, pr.w * w3.z)));
        const float v3 = fmaf(pr.x, w0.w, fmaf(pr.y, w1.w, fmaf(pr.z, w2.w, pr.w * w3.w)));
        const float c0 = coeff * v0, c1 = coeff * v1, c2 = coeff * v2, c3 = coeff * v3;
        S1[4*i+0] += c0;  S2[4*i+0] = fmaf(c0, v0, S2[4*i+0]);
        S1[4*i+1] += c1;  S2[4*i+1] = fmaf(c1, v1, S2[4*i+1]);
        S1[4*i+2] += c2;  S2[4*i+2] = fmaf(c2, v2, S2[4*i+2]);
        S1[4*i+3] += c3;  S2[4*i+3] = fmaf(c3, v3, S2[4*i+3]);
      }
    }

    // ---- reduce across 16 sub-lanes (all lanes keep full sums) ----
    #pragma unroll
    for (int p = 0; p < 16; ++p) { S1[p] += __shfl_xor(S1[p], 4);  S2[p] += __shfl_xor(S2[p], 4);  }
    #pragma unroll
    for (int p = 0; p < 16; ++p) { S1[p] += xor8_dpp(S1[p]);       S2[p] += xor8_dpp(S2[p]);       }
    #pragma unroll
    for (int p = 0; p < 16; ++p) { S1[p] += __shfl_xor(S1[p], 16); S2[p] += __shfl_xor(S2[p], 16); }
    #pragma unroll
    for (int p = 0; p < 16; ++p) { S1[p] += __shfl_xor(S1[p], 32); S2[p] += __shfl_xor(S2[p], 32); }

    // ---- per-class stats: S1 = mu, S2 := hi = 0.5/sigma^2 ----
    const float g2 = 2.0f - rs * inv;        // 2 - sum(coeff), exact
    float logsum = 0.f;
    #pragma unroll
    for (int p = 0; p < 16; ++p) {
      const float m = S1[p];
      float sig = S2[p] - m * m * g2 + EPSF;   // sum coeff*(v-mu)^2 + eps
      sig = fmaxf(sig, 1e-12f);
      logsum += __logf(sig);
      S2[p] = 0.5f * rcpf(sig);
    }
    const float cost = rs * (16.0f * bu + 0.5f * logsum);
    const float aout = rcpf(1.0f + __expf(-LAMB * (ba - cost)));

    if (it == iters - 1) {
      if (sub == 0) {
        float4* om = (float4*)(out_mu + (size_t)pos * 512 + c * 16);
        om[0] = make_float4(S1[0],  S1[1],  S1[2],  S1[3]);
        om[1] = make_float4(S1[4],  S1[5],  S1[6],  S1[7]);
        om[2] = make_float4(S1[8],  S1[9],  S1[10], S1[11]);
        om[3] = make_float4(S1[12], S1[13], S1[14], S1[15]);
        out_a[pos * CC + c] = aout;
      }
    } else {
      // ---- E-step: ln_ap = kc - sum_p v*(A*v + B); A=S2(hi), B:=-2*hi*mu ----
      float D = 0.f;
      #pragma unroll
      for (int p = 0; p < 16; ++p) {
        const float m = S1[p];
        D = fmaf(S2[p] * m, m, D);
        S1[p] = -2.0f * S2[p] * m;
      }
      const float kc = __logf(aout + EPSF) - 0.5f * logsum - 8.0f * LN2PI - D;

      #pragma unroll 3
      for (int k = 0; k < KPER; ++k) {
        const int n = n0 + k;
        const float4* Wp = (const float4*)(wc + n * 512);
        const float4 w0 = Wp[0], w1 = Wp[1], w2 = Wp[2], w3 = Wp[3];
        float s = 0.f;
        #pragma unroll
        for (int i = 0; i < 4; ++i) {
          const float4 pr = *(const float4*)(sP + n * PSTR + i * 4);
          const float v0 = fmaf(pr.x, w0.x, fmaf(pr.y, w1.x, fmaf(pr.z, w2.x, pr.w * w3.x)));
          const float v1 = fmaf(pr.x, w0.y, fmaf(pr.y, w1.y, fmaf(pr.z, w2.y, pr.w * w3.y)));
          const float v2 = fmaf(pr.x, w0.z, fmaf(pr.y, w1.z, fmaf(pr.z, w2.z, pr.w * w3.z)));
          const float v3 = fmaf(pr.x, w0.w, fmaf(pr.y, w1.w, fmaf(pr.z, w2.w, pr.w * w3.w)));
          s = fmaf(fmaf(S2[4*i+0], v0, S1[4*i+0]), v0, s);
          s = fmaf(fmaf(S2[4*i+1], v1, S1[4*i+1]), v1, s);
          s = fmaf(fmaf(S2[4*i+2], v2, S1[4*i+2]), v2, s);
          s = fmaf(fmaf(S2[4*i+3], v3, S1[4*i+3]), v3, s);
        }
        sL[n * RS + c] = kc - s;
      }
      __syncthreads();
      // ---- softmax over classes per n (2 threads per capsule) ----
      if (tid < 2 * NN) {
        const int n = tid >> 1, hf = (tid & 1) << 4;
        float xv[16];
        float mx = -3.0e38f;
        #pragma unroll
        for (int q = 0; q < 16; ++q) { xv[q] = sL[n * RS + hf + q]; mx = fmaxf(mx, xv[q]); }
        mx = fmaxf(mx, __shfl_xor(mx, 1));
        float ssum = 0.f;
        #pragma unroll
        for (int q = 0; q < 16; ++q) { xv[q] = __expf(xv[q] - mx); ssum += xv[q]; }
        ssum += __shfl_xor(ssum, 1);
        const float sc = sA[n] * rcpf(ssum);
        #pragma unroll
        for (int q = 0; q < 16; ++q) sL[n * RS + hf + q] = xv[q] * sc;
      }
      __syncthreads();
    }
  }
}

} // namespace

extern "C" void kernel_launch(void* const* d_in, const int* in_sizes, int n_in,
                              void* d_out, int out_size, void* d_ws, size_t ws_size,
                              hipStream_t stream) {
  const float* x  = (const float*)d_in[0];
  const float* a  = (const float*)d_in[1];
  const float* w  = (const float*)d_in[2];
  const float* bu = (const float*)d_in[3];
  const float* ba = (const float*)d_in[4];
  const int* iters = (const int*)d_in[5];

  float* out_mu = (float*)d_out;                       // 401408
  float* out_a  = out_mu + (size_t)NPOS * CC * 16;     // 25088

  convcaps_em<<<NPOS, 512, 0, stream>>>(x, a, w, bu, ba, iters, out_mu, out_a);
}